// Round 4
// baseline (915.387 us; speedup 1.0000x reference)
//
#include <hip/hip_runtime.h>
#include <hip/hip_bf16.h>
#include <math.h>

typedef __bf16 bf16_t;
typedef __bf16 bf16x8 __attribute__((ext_vector_type(8)));
typedef float  f32x4  __attribute__((ext_vector_type(4)));

typedef __attribute__((address_space(1))) const void GVoid;
typedef __attribute__((address_space(3))) void LVoid;

__device__ __forceinline__ void gld16(const void* g, void* l) {
    // async global->LDS, 16B per lane; LDS dest = wave-uniform base + lane*16
    __builtin_amdgcn_global_load_lds((GVoid*)g, (LVoid*)l, 16, 0, 0);
}

__device__ __forceinline__ float gelu_exact(float v) {
    return 0.5f * v * (1.0f + erff(v * 0.7071067811865475f));
}

// ---------------------------------------------------------------------------
// Tiled transpose + downcast: in f32 (R x C) -> out bf16 (C x R).
// ---------------------------------------------------------------------------
__global__ __launch_bounds__(256) void transpose_f32_bf16(
    const float* __restrict__ in, bf16_t* __restrict__ out, int R, int C)
{
    __shared__ bf16_t tile[64][65];
    const int r0 = blockIdx.y * 64, c0 = blockIdx.x * 64;
    const int t = threadIdx.x, tc = t & 63, tr = t >> 6;
#pragma unroll
    for (int i = 0; i < 16; ++i) {
        int r = tr + i * 4;
        tile[r][tc] = (bf16_t)in[(size_t)(r0 + r) * C + c0 + tc];
    }
    __syncthreads();
#pragma unroll
    for (int i = 0; i < 16; ++i) {
        int r = tr + i * 4;  // row of transposed tile (= original col)
        out[(size_t)(c0 + r) * R + r0 + tc] = tile[tc][r];
    }
}

// ---------------------------------------------------------------------------
// Tiled bf16 transpose (batched): per-head V (1024x64) -> (64x1024).
// ---------------------------------------------------------------------------
__global__ __launch_bounds__(256) void transpose_bf16(
    const bf16_t* __restrict__ in, bf16_t* __restrict__ out,
    int R, int C, size_t inBatch, size_t outBatch)
{
    __shared__ __align__(16) bf16_t tile[64][65];
    const bf16_t* src = in  + (size_t)blockIdx.z * inBatch;
    bf16_t*       dst = out + (size_t)blockIdx.z * outBatch;
    const int r0 = blockIdx.y * 64, c0 = blockIdx.x * 64;
    const int t = threadIdx.x, tc = t & 63, tr = t >> 6;
#pragma unroll
    for (int i = 0; i < 16; ++i) {
        int r = tr + i * 4;
        tile[r][tc] = src[(size_t)(r0 + r) * C + c0 + tc];
    }
    __syncthreads();
#pragma unroll
    for (int i = 0; i < 16; ++i) {
        int r = tr + i * 4;
        dst[(size_t)(c0 + r) * R + r0 + tc] = tile[tc][r];
    }
}

// ---------------------------------------------------------------------------
// LayerNorm over rows of length 1024: f32 in -> bf16 out. One block / row.
// ---------------------------------------------------------------------------
__global__ __launch_bounds__(256) void ln_kernel(
    const float* __restrict__ x, const float* __restrict__ g,
    const float* __restrict__ b, bf16_t* __restrict__ out)
{
    const int row = blockIdx.x, t = threadIdx.x;
    const float* xr = x + (size_t)row * 1024;
    float v[4];
#pragma unroll
    for (int i = 0; i < 4; ++i) v[i] = xr[t * 4 + i];
    float s = v[0] + v[1] + v[2] + v[3];
    float s2 = v[0]*v[0] + v[1]*v[1] + v[2]*v[2] + v[3]*v[3];
#pragma unroll
    for (int o = 1; o < 64; o <<= 1) { s += __shfl_xor(s, o); s2 += __shfl_xor(s2, o); }
    __shared__ float red[8];
    if ((t & 63) == 0) { red[t >> 6] = s; red[4 + (t >> 6)] = s2; }
    __syncthreads();
    s  = red[0] + red[1] + red[2] + red[3];
    s2 = red[4] + red[5] + red[6] + red[7];
    const float mean = s * (1.f / 1024.f);
    const float var  = fmaxf(s2 * (1.f / 1024.f) - mean * mean, 0.f);
    const float rstd = rsqrtf(var + 1e-5f);
#pragma unroll
    for (int i = 0; i < 4; ++i) {
        int c = t * 4 + i;
        out[(size_t)row * 1024 + c] =
            (bf16_t)((v[i] - mean) * rstd * g[c] + b[c]);
    }
}

// ---------------------------------------------------------------------------
// GEMM: C(M,N) = A(M,K) @ B(K,N), B given transposed: Bt(N,K) row-major bf16.
// 128x128 tile, BK=32, 256 threads = 4 waves (2x2), 16x16x32 bf16 MFMA.
// MODE 0: out_bf = acc + bias                      (QKV)
// MODE 1: out_f  = acc + bias + resid_f            (proj / FC2, f32 out)
// MODE 2: out_bf = gelu(acc + bias)                (FC1)
// ---------------------------------------------------------------------------
template <int MODE>
__global__ __launch_bounds__(256) void gemm_bt(
    const bf16_t* __restrict__ A, const bf16_t* __restrict__ Bt,
    const float* __restrict__ bias, const float* __restrict__ resid_f,
    bf16_t* __restrict__ out_bf, float* __restrict__ out_f, int N, int K)
{
    __shared__ __align__(16) bf16_t As[128 * 32];
    __shared__ __align__(16) bf16_t Bs[128 * 32];
    const int t = threadIdx.x;
    const int wv = t >> 6, ln = t & 63;
    const int wx = wv & 1, wy = wv >> 1;
    const int l16 = ln & 15, quad = ln >> 4;
    const int m0 = blockIdx.x * 128, n0 = blockIdx.y * 128;

    f32x4 acc[4][4];
#pragma unroll
    for (int i = 0; i < 4; ++i)
#pragma unroll
        for (int j = 0; j < 4; ++j) acc[i][j] = f32x4{0.f, 0.f, 0.f, 0.f};

    const int arow = t >> 2;           // 0..63
    const int acol = (t & 3) << 3;     // 0,8,16,24
    const bf16_t* gA = A  + (size_t)(m0 + arow) * K + acol;
    const bf16_t* gB = Bt + (size_t)(n0 + arow) * K + acol;
    char* ldsA = (char*)As + wv * 1024;
    char* ldsB = (char*)Bs + wv * 1024;

    for (int kk = 0; kk < K; kk += 32) {
        __syncthreads();
        gld16(gA + kk,                 ldsA);
        gld16(gA + (size_t)64*K + kk,  ldsA + 4096);
        gld16(gB + kk,                 ldsB);
        gld16(gB + (size_t)64*K + kk,  ldsB + 4096);
        __syncthreads();

        bf16x8 af[4], bfr[4];
        const bf16_t* Ab = As + (wy * 64 + l16) * 32 + quad * 8;
        const bf16_t* Bb = Bs + (wx * 64 + l16) * 32 + quad * 8;
#pragma unroll
        for (int i = 0; i < 4; ++i) af[i]  = *(const bf16x8*)(Ab + i * 16 * 32);
#pragma unroll
        for (int j = 0; j < 4; ++j) bfr[j] = *(const bf16x8*)(Bb + j * 16 * 32);
#pragma unroll
        for (int i = 0; i < 4; ++i)
#pragma unroll
            for (int j = 0; j < 4; ++j)
                acc[i][j] = __builtin_amdgcn_mfma_f32_16x16x32_bf16(
                    af[i], bfr[j], acc[i][j], 0, 0, 0);
    }

    // epilogue: C/D layout col=lane&15, row=quad*4+reg
#pragma unroll
    for (int i = 0; i < 4; ++i) {
        const int rowb = m0 + wy * 64 + i * 16 + quad * 4;
#pragma unroll
        for (int j = 0; j < 4; ++j) {
            const int col = n0 + wx * 64 + j * 16 + l16;
            const float bc = bias[col];
#pragma unroll
            for (int r = 0; r < 4; ++r) {
                const size_t idx = (size_t)(rowb + r) * N + col;
                float vv = acc[i][j][r] + bc;
                if (MODE == 0) out_bf[idx] = (bf16_t)vv;
                else if (MODE == 1) out_f[idx] = vv + resid_f[idx];
                else out_bf[idx] = (bf16_t)gelu_exact(vv);
            }
        }
    }
}

// ---------------------------------------------------------------------------
// Flash attention over the "buggy reshape" heads: each of the 128 (b,h) pairs
// is a contiguous (1024 x 64) block of Q/K/V. Vt holds per-head V^T (64x1024).
// Block = (q-tile of 128 rows) x (b,h). 256 threads = 4 waves.
// LDS: Qs 16K | Ks 16K | spare 16K | Vs 16K; Ps(32K) overlays Ks+spare.
// ---------------------------------------------------------------------------
__global__ __launch_bounds__(256) void attn_kernel(
    const bf16_t* __restrict__ Q, const bf16_t* __restrict__ K,
    const bf16_t* __restrict__ Vt, bf16_t* __restrict__ O)
{
    __shared__ __align__(16) bf16_t smem[32768];   // 64 KiB
    bf16_t* Qs = smem;            // 8192: 128x64
    bf16_t* Ks = smem + 8192;     // 8192: 128x64
    bf16_t* Ps = smem + 8192;     // 16384: 128x128 (overlays Ks + spare)
    bf16_t* Vs = smem + 24576;    // 8192: 64x128 (V^T tile)

    const int t = threadIdx.x;
    const int wv = t >> 6, ln = t & 63;
    const int l16 = ln & 15, quad = ln >> 4;
    const int qt = blockIdx.x, bh = blockIdx.y;
    const size_t hb = (size_t)bh << 16;   // 65536 elems per head

    {   // stage Q tile (fully contiguous 16 KiB)
        const bf16_t* gq = Q + hb + (size_t)qt * 8192 + t * 8;
#pragma unroll
        for (int i = 0; i < 4; ++i)
            gld16(gq + i * 2048, (char*)Qs + (i * 2048 + wv * 512) * 2);
    }

    float m_run[2][4], l_run[2][4];
    f32x4 acc_o[2][4];
#pragma unroll
    for (int rt = 0; rt < 2; ++rt)
#pragma unroll
        for (int r = 0; r < 4; ++r) { m_run[rt][r] = -INFINITY; l_run[rt][r] = 0.f; }
#pragma unroll
    for (int rt = 0; rt < 2; ++rt)
#pragma unroll
        for (int dt = 0; dt < 4; ++dt) acc_o[rt][dt] = f32x4{0.f, 0.f, 0.f, 0.f};

    for (int j = 0; j < 8; ++j) {
        __syncthreads();   // prior iter done reading Ks(Ps)/Vs
        {
            const bf16_t* gk = K + hb + (size_t)j * 8192 + t * 8;
#pragma unroll
            for (int i = 0; i < 4; ++i)
                gld16(gk + i * 2048, (char*)Ks + (i * 2048 + wv * 512) * 2);
            // Vt tile: rows d=0..63 (stride 1024), cols j*128..+128
            const bf16_t* gv = Vt + hb + (size_t)(t >> 4) * 1024 + j * 128 + (t & 15) * 8;
#pragma unroll
            for (int i = 0; i < 4; ++i)
                gld16(gv + (size_t)i * 16 * 1024, (char*)Vs + (i * 2048 + wv * 512) * 2);
        }
        __syncthreads();

        // S = Q @ K^T for this wave's 32 rows x 128 cols
        f32x4 accs[2][8];
#pragma unroll
        for (int rt = 0; rt < 2; ++rt)
#pragma unroll
            for (int nt = 0; nt < 8; ++nt) accs[rt][nt] = f32x4{0.f, 0.f, 0.f, 0.f};
#pragma unroll
        for (int ks = 0; ks < 2; ++ks) {
            bf16x8 aq[2];
#pragma unroll
            for (int rt = 0; rt < 2; ++rt)
                aq[rt] = *(const bf16x8*)(Qs + (wv*32 + rt*16 + l16) * 64 + ks*32 + quad*8);
#pragma unroll
            for (int nt = 0; nt < 8; ++nt) {
                bf16x8 bk = *(const bf16x8*)(Ks + (nt*16 + l16) * 64 + ks*32 + quad*8);
#pragma unroll
                for (int rt = 0; rt < 2; ++rt)
                    accs[rt][nt] = __builtin_amdgcn_mfma_f32_16x16x32_bf16(
                        aq[rt], bk, accs[rt][nt], 0, 0, 0);
            }
        }

        // online softmax (registers + quad shuffles only)
        const float sc = 0.125f;   // hd^-0.5
#pragma unroll
        for (int rt = 0; rt < 2; ++rt) {
#pragma unroll
            for (int r = 0; r < 4; ++r) {
                float mx = accs[rt][0][r];
#pragma unroll
                for (int nt = 1; nt < 8; ++nt) mx = fmaxf(mx, accs[rt][nt][r]);
                mx *= sc;
                mx = fmaxf(mx, __shfl_xor(mx, 1));
                mx = fmaxf(mx, __shfl_xor(mx, 2));
                mx = fmaxf(mx, __shfl_xor(mx, 4));
                mx = fmaxf(mx, __shfl_xor(mx, 8));
                float mnew  = fmaxf(m_run[rt][r], mx);
                float alpha = __expf(m_run[rt][r] - mnew);
                m_run[rt][r] = mnew;
                float rs = 0.f;
#pragma unroll
                for (int nt = 0; nt < 8; ++nt) {
                    float p = __expf(accs[rt][nt][r] * sc - mnew);
                    accs[rt][nt][r] = p;
                    rs += p;
                }
                rs += __shfl_xor(rs, 1); rs += __shfl_xor(rs, 2);
                rs += __shfl_xor(rs, 4); rs += __shfl_xor(rs, 8);
                l_run[rt][r] = l_run[rt][r] * alpha + rs;
#pragma unroll
                for (int dt = 0; dt < 4; ++dt) acc_o[rt][dt][r] *= alpha;
            }
        }

        __syncthreads();   // all waves done reading Ks before Ps overwrites it
        // P: C-layout -> LDS row-major (row, seqK) for A-operand reads
#pragma unroll
        for (int rt = 0; rt < 2; ++rt)
#pragma unroll
            for (int nt = 0; nt < 8; ++nt)
#pragma unroll
                for (int r = 0; r < 4; ++r)
                    Ps[(wv*32 + rt*16 + quad*4 + r) * 128 + nt*16 + l16] =
                        (bf16_t)accs[rt][nt][r];
        __syncthreads();

        // O += P @ V  (A = Ps rows of this wave, Bt = Vs (d x seqK))
#pragma unroll
        for (int ks = 0; ks < 4; ++ks) {
            bf16x8 ap[2];
#pragma unroll
            for (int rt = 0; rt < 2; ++rt)
                ap[rt] = *(const bf16x8*)(Ps + (wv*32 + rt*16 + l16) * 128 + ks*32 + quad*8);
#pragma unroll
            for (int dt = 0; dt < 4; ++dt) {
                bf16x8 bv = *(const bf16x8*)(Vs + (dt*16 + l16) * 128 + ks*32 + quad*8);
#pragma unroll
                for (int rt = 0; rt < 2; ++rt)
                    acc_o[rt][dt] = __builtin_amdgcn_mfma_f32_16x16x32_bf16(
                        ap[rt], bv, acc_o[rt][dt], 0, 0, 0);
            }
        }
    }

    // write O with head-transpose: row m, col h*64+d
    const int b = bh >> 4, h = bh & 15;
#pragma unroll
    for (int rt = 0; rt < 2; ++rt) {
#pragma unroll
        for (int r = 0; r < 4; ++r) {
            const int m = qt * 128 + wv * 32 + rt * 16 + quad * 4 + r;
            const float inv = 1.f / l_run[rt][r];
#pragma unroll
            for (int dt = 0; dt < 4; ++dt) {
                const int d = dt * 16 + l16;
                O[((size_t)b * 1024 + m) * 1024 + h * 64 + d] =
                    (bf16_t)(acc_o[rt][dt][r] * inv);
            }
        }
    }
}

// ---------------------------------------------------------------------------
extern "C" void kernel_launch(void* const* d_in, const int* in_sizes, int n_in,
                              void* d_out, int out_size, void* d_ws, size_t ws_size,
                              hipStream_t stream)
{
    (void)in_sizes; (void)n_in;
    const size_t MB = 1ull << 20;

    // Diagnostic fallback: finite absmax (~5.94) next round => ws starvation.
    if (ws_size < 64 * MB) {
        hipMemsetAsync(d_out, 0, (size_t)out_size * sizeof(float), stream);
        return;
    }

    // f32 storage at the boundaries (per reference dtypes), bf16 internal.
    const float* x  = (const float*)d_in[0];
    const float* g1 = (const float*)d_in[1];
    const float* b1 = (const float*)d_in[2];
    const float* Wq = (const float*)d_in[3];
    const float* bq = (const float*)d_in[4];
    const float* Wk = (const float*)d_in[5];
    const float* bk = (const float*)d_in[6];
    const float* Wv = (const float*)d_in[7];
    const float* bv = (const float*)d_in[8];
    const float* Wp = (const float*)d_in[9];
    const float* bp = (const float*)d_in[10];
    const float* g2 = (const float*)d_in[11];
    const float* b2 = (const float*)d_in[12];
    const float* W1 = (const float*)d_in[13];
    const float* c1 = (const float*)d_in[14];
    const float* W2 = (const float*)d_in[15];
    const float* c2 = (const float*)d_in[16];

    // Workspace plan (64 MB), 16 MB slots:
    //   S0 (0-16):  K bf16            -> W2T (8MB) after attention
    //   S1 (16-32): V -> Ob -> hid    (bf16)
    //   S2 (32-48): h1 -> Vt -> h2    (bf16)
    //   S3 (48-64): WqT|WkT|WvT|WpT (2MB each) | W1T (8MB)
    //   d_out (32 MB f32): Q bf16 (first 16MB) -> x2 f32 -> final out f32
    char* ws = (char*)d_ws;
    bf16_t* Kb  = (bf16_t*)(ws);
    bf16_t* Vb  = (bf16_t*)(ws + 16 * MB);
    bf16_t* Cs  = (bf16_t*)(ws + 32 * MB);
    bf16_t* WqT = (bf16_t*)(ws + 48 * MB);
    bf16_t* WkT = (bf16_t*)(ws + 50 * MB);
    bf16_t* WvT = (bf16_t*)(ws + 52 * MB);
    bf16_t* WpT = (bf16_t*)(ws + 54 * MB);
    bf16_t* W1T = (bf16_t*)(ws + 56 * MB);   // 8MB
    bf16_t* W2T = Kb;                        // 8MB, after K dead
    bf16_t* Qb  = (bf16_t*)d_out;            // Q in d_out (16MB of 32MB)
    bf16_t* Ob  = Vb;                        // after V transposed
    bf16_t* hid = Vb;                        // after Ob consumed
    bf16_t* h2  = Cs;                        // after Vt consumed
    float*  x2  = (float*)d_out;             // after Q consumed
    float*  out = (float*)d_out;

    const dim3 blk(256);

    // weight transposes (f32 -> bf16, (N,K) layout)
    transpose_f32_bf16<<<dim3(16, 16), blk, 0, stream>>>(Wq, WqT, 1024, 1024);
    transpose_f32_bf16<<<dim3(16, 16), blk, 0, stream>>>(Wk, WkT, 1024, 1024);
    transpose_f32_bf16<<<dim3(16, 16), blk, 0, stream>>>(Wv, WvT, 1024, 1024);
    transpose_f32_bf16<<<dim3(16, 16), blk, 0, stream>>>(Wp, WpT, 1024, 1024);
    transpose_f32_bf16<<<dim3(64, 16), blk, 0, stream>>>(W1, W1T, 1024, 4096);

    // LN1: x(f32) -> h1 bf16 (S2)
    ln_kernel<<<8192, blk, 0, stream>>>(x, g1, b1, Cs);

    // QKV GEMMs: Q -> d_out(bf16), K -> S0, V -> S1
    gemm_bt<0><<<dim3(64, 8), blk, 0, stream>>>(Cs, WqT, bq, nullptr, Qb, nullptr, 1024, 1024);
    gemm_bt<0><<<dim3(64, 8), blk, 0, stream>>>(Cs, WkT, bk, nullptr, Kb, nullptr, 1024, 1024);
    gemm_bt<0><<<dim3(64, 8), blk, 0, stream>>>(Cs, WvT, bv, nullptr, Vb, nullptr, 1024, 1024);

    // per-head V transpose (128 heads of 1024x64 -> 64x1024): V(S1) -> Vt(S2)
    transpose_bf16<<<dim3(1, 16, 128), blk, 0, stream>>>(Vb, Cs, 1024, 64, 65536, 65536);

    // flash attention: Q(d_out), K(S0), Vt(S2) -> Ob(S1)
    attn_kernel<<<dim3(8, 128), blk, 0, stream>>>(Qb, Kb, Cs, Ob);

    // W2 transpose into dead K slot (f32 -> bf16)
    transpose_f32_bf16<<<dim3(16, 64), blk, 0, stream>>>(W2, W2T, 4096, 1024);

    // output projection + residual: Ob @ Wp + bp + x -> x2 (f32, d_out)
    gemm_bt<1><<<dim3(64, 8), blk, 0, stream>>>(Ob, WpT, bp, x, nullptr, x2, 1024, 1024);

    // LN2: x2(f32, d_out) -> h2 bf16 (S2)
    ln_kernel<<<8192, blk, 0, stream>>>(x2, g2, b2, h2);

    // MLP in 4 passes of 2048 rows; hid(S1) = 2048x4096 bf16 = 16MB.
    // FC2 adds x2 residual and writes out in place (one-to-one RMW, safe).
    for (int p = 0; p < 4; ++p) {
        const size_t r0 = (size_t)p * 2048;
        gemm_bt<2><<<dim3(16, 32), blk, 0, stream>>>(
            h2 + r0 * 1024, W1T, c1, nullptr, hid, nullptr, 4096, 1024);
        gemm_bt<1><<<dim3(16, 8), blk, 0, stream>>>(
            hid, W2T, c2, x2 + r0 * 1024, nullptr, out + r0 * 1024, 1024, 4096);
    }
}

// Round 5
// 666.417 us; speedup vs baseline: 1.3736x; 1.3736x over previous
//
#include <hip/hip_runtime.h>
#include <hip/hip_bf16.h>
#include <math.h>

typedef __bf16 bf16_t;
typedef __bf16 bf16x4 __attribute__((ext_vector_type(4)));
typedef __bf16 bf16x8 __attribute__((ext_vector_type(8)));
typedef float  f32x4  __attribute__((ext_vector_type(4)));

typedef __attribute__((address_space(1))) const void GVoid;
typedef __attribute__((address_space(3))) void LVoid;

__device__ __forceinline__ void gld16(const void* g, void* l) {
    __builtin_amdgcn_global_load_lds((GVoid*)g, (LVoid*)l, 16, 0, 0);
}

__device__ __forceinline__ float gelu_exact(float v) {
    return 0.5f * v * (1.0f + erff(v * 0.7071067811865475f));
}

// ---------------------------------------------------------------------------
// Tiled transpose + downcast (batched): f32 (R x C) -> bf16 (C x R) per batch.
// ---------------------------------------------------------------------------
__global__ __launch_bounds__(256) void transpose_f32_bf16(
    const float* __restrict__ in, bf16_t* __restrict__ out,
    int R, int C, size_t inBatch, size_t outBatch)
{
    __shared__ bf16_t tile[64][65];
    const float* src = in  + (size_t)blockIdx.z * inBatch;
    bf16_t*      dst = out + (size_t)blockIdx.z * outBatch;
    const int r0 = blockIdx.y * 64, c0 = blockIdx.x * 64;
    const int t = threadIdx.x, tc = t & 63, tr = t >> 6;
#pragma unroll
    for (int i = 0; i < 16; ++i) {
        int r = tr + i * 4;
        tile[r][tc] = (bf16_t)src[(size_t)(r0 + r) * C + c0 + tc];
    }
    __syncthreads();
#pragma unroll
    for (int i = 0; i < 16; ++i) {
        int r = tr + i * 4;
        dst[(size_t)(c0 + r) * R + r0 + tc] = tile[tc][r];
    }
}

// ---------------------------------------------------------------------------
// Tiled bf16 transpose (batched): per-head V (1024x64) -> (64x1024).
// ---------------------------------------------------------------------------
__global__ __launch_bounds__(256) void transpose_bf16(
    const bf16_t* __restrict__ in, bf16_t* __restrict__ out,
    int R, int C, size_t inBatch, size_t outBatch)
{
    __shared__ __align__(16) bf16_t tile[64][65];
    const bf16_t* src = in  + (size_t)blockIdx.z * inBatch;
    bf16_t*       dst = out + (size_t)blockIdx.z * outBatch;
    const int r0 = blockIdx.y * 64, c0 = blockIdx.x * 64;
    const int t = threadIdx.x, tc = t & 63, tr = t >> 6;
#pragma unroll
    for (int i = 0; i < 16; ++i) {
        int r = tr + i * 4;
        tile[r][tc] = src[(size_t)(r0 + r) * C + c0 + tc];
    }
    __syncthreads();
#pragma unroll
    for (int i = 0; i < 16; ++i) {
        int r = tr + i * 4;
        dst[(size_t)(c0 + r) * R + r0 + tc] = tile[tc][r];
    }
}

// ---------------------------------------------------------------------------
// LayerNorm rows of 1024: f32 in -> bf16 out. One 256-thread block / row.
// ---------------------------------------------------------------------------
__global__ __launch_bounds__(256) void ln_kernel(
    const float* __restrict__ x, const float* __restrict__ g,
    const float* __restrict__ b, bf16_t* __restrict__ out)
{
    const int row = blockIdx.x, t = threadIdx.x;
    const float* xr = x + (size_t)row * 1024;
    float v[4];
#pragma unroll
    for (int i = 0; i < 4; ++i) v[i] = xr[t * 4 + i];
    float s = v[0] + v[1] + v[2] + v[3];
    float s2 = v[0]*v[0] + v[1]*v[1] + v[2]*v[2] + v[3]*v[3];
#pragma unroll
    for (int o = 1; o < 64; o <<= 1) { s += __shfl_xor(s, o); s2 += __shfl_xor(s2, o); }
    __shared__ float red[8];
    if ((t & 63) == 0) { red[t >> 6] = s; red[4 + (t >> 6)] = s2; }
    __syncthreads();
    s  = red[0] + red[1] + red[2] + red[3];
    s2 = red[4] + red[5] + red[6] + red[7];
    const float mean = s * (1.f / 1024.f);
    const float var  = fmaxf(s2 * (1.f / 1024.f) - mean * mean, 0.f);
    const float rstd = rsqrtf(var + 1e-5f);
#pragma unroll
    for (int i = 0; i < 4; ++i) {
        int c = t * 4 + i;
        out[(size_t)row * 1024 + c] =
            (bf16_t)((v[i] - mean) * rstd * g[c] + b[c]);
    }
}

// ---------------------------------------------------------------------------
// GEMM: C(M,N) = A(M,K) @ B(K,N), B transposed: Bt(N,K) row-major bf16.
// 128x128 tile, BK=32, 4 waves (2x2), 16x16x32 bf16 MFMA.
// MODE 0: out_bf = acc + bias
// MODE 1: out_f  = acc + bias + resid_f   (resid may alias out)
// MODE 2: out_bf = gelu(acc + bias)
// MODE 5: out_f += acc                    (K-chunk accumulation)
// ---------------------------------------------------------------------------
template <int MODE>
__global__ __launch_bounds__(256) void gemm_bt(
    const bf16_t* __restrict__ A, const bf16_t* __restrict__ Bt,
    const float* __restrict__ bias, const float* resid_f,
    bf16_t* __restrict__ out_bf, float* out_f, int N, int K)
{
    __shared__ __align__(16) bf16_t As[128 * 32];
    __shared__ __align__(16) bf16_t Bs[128 * 32];
    const int t = threadIdx.x;
    const int wv = t >> 6, ln = t & 63;
    const int wx = wv & 1, wy = wv >> 1;
    const int l16 = ln & 15, quad = ln >> 4;
    const int m0 = blockIdx.x * 128, n0 = blockIdx.y * 128;

    f32x4 acc[4][4];
#pragma unroll
    for (int i = 0; i < 4; ++i)
#pragma unroll
        for (int j = 0; j < 4; ++j) acc[i][j] = f32x4{0.f, 0.f, 0.f, 0.f};

    const int arow = t >> 2;
    const int acol = (t & 3) << 3;
    const bf16_t* gA = A  + (size_t)(m0 + arow) * K + acol;
    const bf16_t* gB = Bt + (size_t)(n0 + arow) * K + acol;
    char* ldsA = (char*)As + wv * 1024;
    char* ldsB = (char*)Bs + wv * 1024;

    for (int kk = 0; kk < K; kk += 32) {
        __syncthreads();
        gld16(gA + kk,                 ldsA);
        gld16(gA + (size_t)64*K + kk,  ldsA + 4096);
        gld16(gB + kk,                 ldsB);
        gld16(gB + (size_t)64*K + kk,  ldsB + 4096);
        __syncthreads();

        bf16x8 af[4], bfr[4];
        const bf16_t* Ab = As + (wy * 64 + l16) * 32 + quad * 8;
        const bf16_t* Bb = Bs + (wx * 64 + l16) * 32 + quad * 8;
#pragma unroll
        for (int i = 0; i < 4; ++i) af[i]  = *(const bf16x8*)(Ab + i * 16 * 32);
#pragma unroll
        for (int j = 0; j < 4; ++j) bfr[j] = *(const bf16x8*)(Bb + j * 16 * 32);
#pragma unroll
        for (int i = 0; i < 4; ++i)
#pragma unroll
            for (int j = 0; j < 4; ++j)
                acc[i][j] = __builtin_amdgcn_mfma_f32_16x16x32_bf16(
                    af[i], bfr[j], acc[i][j], 0, 0, 0);
    }

#pragma unroll
    for (int i = 0; i < 4; ++i) {
        const int rowb = m0 + wy * 64 + i * 16 + quad * 4;
#pragma unroll
        for (int j = 0; j < 4; ++j) {
            const int col = n0 + wx * 64 + j * 16 + l16;
            const float bc = bias[col];
#pragma unroll
            for (int r = 0; r < 4; ++r) {
                const size_t idx = (size_t)(rowb + r) * N + col;
                float vv = acc[i][j][r] + bc;
                if (MODE == 0) out_bf[idx] = (bf16_t)vv;
                else if (MODE == 1) out_f[idx] = vv + resid_f[idx];
                else if (MODE == 2) out_bf[idx] = (bf16_t)gelu_exact(vv);
                else out_f[idx] += acc[i][j][r];
            }
        }
    }
}

// ---------------------------------------------------------------------------
// Fused QKV GEMM: A(8192x1024) @ [Wq|Wk|Wv]^T (3072x1024 concat Bt).
// Per-block output segment is uniform (n0 multiple of 128, segs of 1024).
// ---------------------------------------------------------------------------
__global__ __launch_bounds__(256) void gemm_qkv(
    const bf16_t* __restrict__ A, const bf16_t* __restrict__ Bt,
    const float* __restrict__ bq, const float* __restrict__ bk,
    const float* __restrict__ bv,
    bf16_t* __restrict__ Qo, bf16_t* __restrict__ Ko, bf16_t* __restrict__ Vo,
    int K)
{
    __shared__ __align__(16) bf16_t As[128 * 32];
    __shared__ __align__(16) bf16_t Bs[128 * 32];
    const int t = threadIdx.x;
    const int wv = t >> 6, ln = t & 63;
    const int wx = wv & 1, wy = wv >> 1;
    const int l16 = ln & 15, quad = ln >> 4;
    const int m0 = blockIdx.x * 128, n0 = blockIdx.y * 128;

    f32x4 acc[4][4];
#pragma unroll
    for (int i = 0; i < 4; ++i)
#pragma unroll
        for (int j = 0; j < 4; ++j) acc[i][j] = f32x4{0.f, 0.f, 0.f, 0.f};

    const int arow = t >> 2;
    const int acol = (t & 3) << 3;
    const bf16_t* gA = A  + (size_t)(m0 + arow) * K + acol;
    const bf16_t* gB = Bt + (size_t)(n0 + arow) * K + acol;
    char* ldsA = (char*)As + wv * 1024;
    char* ldsB = (char*)Bs + wv * 1024;

    for (int kk = 0; kk < K; kk += 32) {
        __syncthreads();
        gld16(gA + kk,                 ldsA);
        gld16(gA + (size_t)64*K + kk,  ldsA + 4096);
        gld16(gB + kk,                 ldsB);
        gld16(gB + (size_t)64*K + kk,  ldsB + 4096);
        __syncthreads();

        bf16x8 af[4], bfr[4];
        const bf16_t* Ab = As + (wy * 64 + l16) * 32 + quad * 8;
        const bf16_t* Bb = Bs + (wx * 64 + l16) * 32 + quad * 8;
#pragma unroll
        for (int i = 0; i < 4; ++i) af[i]  = *(const bf16x8*)(Ab + i * 16 * 32);
#pragma unroll
        for (int j = 0; j < 4; ++j) bfr[j] = *(const bf16x8*)(Bb + j * 16 * 32);
#pragma unroll
        for (int i = 0; i < 4; ++i)
#pragma unroll
            for (int j = 0; j < 4; ++j)
                acc[i][j] = __builtin_amdgcn_mfma_f32_16x16x32_bf16(
                    af[i], bfr[j], acc[i][j], 0, 0, 0);
    }

    const int which = n0 >> 10;                         // block-uniform
    const float* bias = which == 0 ? bq : (which == 1 ? bk : bv);
    bf16_t* outp      = which == 0 ? Qo : (which == 1 ? Ko : Vo);
    const int nloc = n0 & 1023;
#pragma unroll
    for (int i = 0; i < 4; ++i) {
        const int rowb = m0 + wy * 64 + i * 16 + quad * 4;
#pragma unroll
        for (int j = 0; j < 4; ++j) {
            const int col = nloc + wx * 64 + j * 16 + l16;
            const float bc = bias[col];
#pragma unroll
            for (int r = 0; r < 4; ++r)
                outp[(size_t)(rowb + r) * 1024 + col] = (bf16_t)(acc[i][j][r] + bc);
        }
    }
}

// ---------------------------------------------------------------------------
// Flash attention, conflict-free LDS. 128 (b,h) heads, each a contiguous
// (1024 x 64) block of Q/K; Vt = per-head V^T (64 x 1024).
// Block = (128-row q-tile) x head; 4 waves, wave owns 32 q-rows.
// Computes S^T = K.Q^T so P leaves MFMA with 4 consecutive k per lane
// (packed b64 writes). Padded strides: K 72, V/P 136 (all <=2-way).
// LDS: Vs 64x136 | Ks 128x72 overlaid by Ps 128x136 = 52224 B.
// ---------------------------------------------------------------------------
__global__ __launch_bounds__(256, 2) void attn_kernel(
    const bf16_t* __restrict__ Q, const bf16_t* __restrict__ K,
    const bf16_t* __restrict__ Vt, bf16_t* __restrict__ O)
{
    __shared__ __align__(16) bf16_t smem[26112];
    bf16_t* Vs = smem;             // 64*136 = 8704 elems
    bf16_t* Ks = smem + 8704;      // 128*72 = 9216 elems
    bf16_t* Ps = smem + 8704;      // 128*136 = 17408 elems (overlays Ks)

    const int t = threadIdx.x;
    const int wv = t >> 6, ln = t & 63;
    const int l16 = ln & 15, quad = ln >> 4;
    const int qt = blockIdx.x, bh = blockIdx.y;
    const size_t hb = (size_t)bh << 16;

    // Q fragments resident in registers (B-operand of S^T MFMA)
    bf16x8 qf[2][2];
#pragma unroll
    for (int rt = 0; rt < 2; ++rt)
#pragma unroll
        for (int ks = 0; ks < 2; ++ks)
            qf[rt][ks] = *(const bf16x8*)(Q + hb +
                (size_t)(qt*128 + wv*32 + rt*16 + l16) * 64 + ks*32 + quad*8);

    float m_run[2] = {-INFINITY, -INFINITY};
    float l_run[2] = {0.f, 0.f};
    f32x4 acc_o[2][4];
#pragma unroll
    for (int rt = 0; rt < 2; ++rt)
#pragma unroll
        for (int dt = 0; dt < 4; ++dt) acc_o[rt][dt] = f32x4{0.f, 0.f, 0.f, 0.f};

    const int krow = t >> 3, kcol = (t & 7) << 3;    // K stage: 32 rows/step
    const int vrow = t >> 4, vcol = (t & 15) << 3;   // V stage: 16 rows/step
    const float sc = 0.125f;                          // hd^-0.5

    for (int j = 0; j < 8; ++j) {
        bf16x8 kg[4], vg[4];
#pragma unroll
        for (int i = 0; i < 4; ++i) {
            kg[i] = *(const bf16x8*)(K  + hb + (size_t)(j*128 + i*32 + krow)*64 + kcol);
            vg[i] = *(const bf16x8*)(Vt + hb + (size_t)(i*16 + vrow)*1024 + j*128 + vcol);
        }
        __syncthreads();            // prior PV done reading Ps/Vs
#pragma unroll
        for (int i = 0; i < 4; ++i) {
            *(bf16x8*)(Ks + (i*32 + krow)*72 + kcol)  = kg[i];
            *(bf16x8*)(Vs + (i*16 + vrow)*136 + vcol) = vg[i];
        }
        __syncthreads();            // staging visible

        // S^T[n][m]: rows n = nt*16+quad*4+r, cols m = rt*16+l16 (+wv*32)
        f32x4 accs[8][2];
#pragma unroll
        for (int nt = 0; nt < 8; ++nt)
#pragma unroll
            for (int rt = 0; rt < 2; ++rt) accs[nt][rt] = f32x4{0.f, 0.f, 0.f, 0.f};
#pragma unroll
        for (int ks = 0; ks < 2; ++ks)
#pragma unroll
            for (int nt = 0; nt < 8; ++nt) {
                bf16x8 kf = *(const bf16x8*)(Ks + (nt*16 + l16)*72 + ks*32 + quad*8);
#pragma unroll
                for (int rt = 0; rt < 2; ++rt)
                    accs[nt][rt] = __builtin_amdgcn_mfma_f32_16x16x32_bf16(
                        kf, qf[rt][ks], accs[nt][rt], 0, 0, 0);
            }

        // online softmax over n, per q-row m = rt*16+l16 (replicated per quad)
#pragma unroll
        for (int rt = 0; rt < 2; ++rt) {
            float mx = -INFINITY;
#pragma unroll
            for (int nt = 0; nt < 8; ++nt)
#pragma unroll
                for (int r = 0; r < 4; ++r) mx = fmaxf(mx, accs[nt][rt][r]);
            mx *= sc;
            mx = fmaxf(mx, __shfl_xor(mx, 16));
            mx = fmaxf(mx, __shfl_xor(mx, 32));
            const float mnew  = fmaxf(m_run[rt], mx);
            const float alpha = __expf(m_run[rt] - mnew);
            m_run[rt] = mnew;
            float rs = 0.f;
#pragma unroll
            for (int nt = 0; nt < 8; ++nt)
#pragma unroll
                for (int r = 0; r < 4; ++r) {
                    float p = __expf(accs[nt][rt][r] * sc - mnew);
                    accs[nt][rt][r] = p;
                    rs += p;
                }
            rs += __shfl_xor(rs, 16);
            rs += __shfl_xor(rs, 32);
            l_run[rt] = l_run[rt] * alpha + rs;
            // rescale O rows quad*4+r with that row's alpha (lane l16 = row)
#pragma unroll
            for (int r = 0; r < 4; ++r) {
                const float af = __shfl(alpha, quad*4 + r, 16);
#pragma unroll
                for (int dt = 0; dt < 4; ++dt) acc_o[rt][dt][r] *= af;
            }
        }

        __syncthreads();            // all waves done reading Ks
        // P write: 4 consecutive k per lane -> b64, row-major stride 136
#pragma unroll
        for (int rt = 0; rt < 2; ++rt) {
            const int mrow = wv*32 + rt*16 + l16;
#pragma unroll
            for (int nt = 0; nt < 8; ++nt) {
                bf16x4 pk;
#pragma unroll
                for (int r = 0; r < 4; ++r) pk[r] = (bf16_t)accs[nt][rt][r];
                *(bf16x4*)(Ps + mrow*136 + nt*16 + quad*4) = pk;
            }
        }
        // PV: each wave reads only its own 32 P-rows -> no barrier needed
#pragma unroll
        for (int ks = 0; ks < 4; ++ks) {
            bf16x8 ap[2];
#pragma unroll
            for (int rt = 0; rt < 2; ++rt)
                ap[rt] = *(const bf16x8*)(Ps + (wv*32 + rt*16 + l16)*136 + ks*32 + quad*8);
#pragma unroll
            for (int dt = 0; dt < 4; ++dt) {
                bf16x8 bvv = *(const bf16x8*)(Vs + (dt*16 + l16)*136 + ks*32 + quad*8);
#pragma unroll
                for (int rt = 0; rt < 2; ++rt)
                    acc_o[rt][dt] = __builtin_amdgcn_mfma_f32_16x16x32_bf16(
                        ap[rt], bvv, acc_o[rt][dt], 0, 0, 0);
            }
        }
    }

    // epilogue: O rows m = quad*4+r, cols d = dt*16+l16; head-interleave out
    const int b = bh >> 4, h = bh & 15;
#pragma unroll
    for (int rt = 0; rt < 2; ++rt) {
#pragma unroll
        for (int r = 0; r < 4; ++r) {
            const float inv = 1.f / __shfl(l_run[rt], quad*4 + r, 16);
            const int m = qt*128 + wv*32 + rt*16 + quad*4 + r;
#pragma unroll
            for (int dt = 0; dt < 4; ++dt) {
                const int d = dt*16 + l16;
                O[((size_t)b*1024 + m)*1024 + h*64 + d] =
                    (bf16_t)(acc_o[rt][dt][r] * inv);
            }
        }
    }
}

// ---------------------------------------------------------------------------
extern "C" void kernel_launch(void* const* d_in, const int* in_sizes, int n_in,
                              void* d_out, int out_size, void* d_ws, size_t ws_size,
                              hipStream_t stream)
{
    (void)in_sizes; (void)n_in;
    const size_t MB = 1ull << 20;
    if (ws_size < 64 * MB) {
        hipMemsetAsync(d_out, 0, (size_t)out_size * sizeof(float), stream);
        return;
    }

    const float* x  = (const float*)d_in[0];
    const float* g1 = (const float*)d_in[1];
    const float* b1 = (const float*)d_in[2];
    const float* Wq = (const float*)d_in[3];
    const float* bq = (const float*)d_in[4];
    const float* Wk = (const float*)d_in[5];
    const float* bk = (const float*)d_in[6];
    const float* Wv = (const float*)d_in[7];
    const float* bv = (const float*)d_in[8];
    const float* Wp = (const float*)d_in[9];
    const float* bp = (const float*)d_in[10];
    const float* g2 = (const float*)d_in[11];
    const float* b2 = (const float*)d_in[12];
    const float* W1 = (const float*)d_in[13];
    const float* c1 = (const float*)d_in[14];
    const float* W2 = (const float*)d_in[15];
    const float* c2 = (const float*)d_in[16];

    // Workspace (64 MB), 16 MB slots:
    //   S0: K bf16 -> W2T (4 chunked 1024x1024, 8 MB) after attention
    //   S1: V -> attn-out Ob -> hid chunk (8192x1024 bf16)
    //   S2: h1 -> Vt -> h2
    //   S3: WqT|WkT|WvT (contiguous, QKV-fused Bt) | WpT | W1T (8 MB)
    //   d_out (32 MB f32): Q bf16 -> x2 f32 -> final out (FC2 RMW in place)
    char* ws = (char*)d_ws;
    bf16_t* Kb  = (bf16_t*)(ws);
    bf16_t* Vb  = (bf16_t*)(ws + 16 * MB);
    bf16_t* Cs  = (bf16_t*)(ws + 32 * MB);
    bf16_t* WqT = (bf16_t*)(ws + 48 * MB);   // +WkT,+WvT contiguous (6 MB)
    bf16_t* WpT = (bf16_t*)(ws + 54 * MB);
    bf16_t* W1T = (bf16_t*)(ws + 56 * MB);   // 8 MB (4096x1024)
    bf16_t* W2T = Kb;                        // 8 MB: 4 chunks of 1024x1024
    bf16_t* Qb  = (bf16_t*)d_out;
    bf16_t* Ob  = Vb;
    bf16_t* hid = Vb;
    bf16_t* h2  = Cs;
    float*  x2  = (float*)d_out;
    float*  outf = (float*)d_out;

    const dim3 blk(256);

    // weight transposes (f32 -> bf16, (N,K)); Wq/Wk/Wv land contiguous
    transpose_f32_bf16<<<dim3(16, 16, 1), blk, 0, stream>>>(Wq, WqT,            1024, 1024, 0, 0);
    transpose_f32_bf16<<<dim3(16, 16, 1), blk, 0, stream>>>(Wk, WqT + 1024*1024, 1024, 1024, 0, 0);
    transpose_f32_bf16<<<dim3(16, 16, 1), blk, 0, stream>>>(Wv, WqT + 2*1024*1024, 1024, 1024, 0, 0);
    transpose_f32_bf16<<<dim3(16, 16, 1), blk, 0, stream>>>(Wp, WpT,            1024, 1024, 0, 0);
    transpose_f32_bf16<<<dim3(64, 16, 1), blk, 0, stream>>>(W1, W1T,            1024, 4096, 0, 0);

    // LN1: x -> h1 (Cs)
    ln_kernel<<<8192, blk, 0, stream>>>(x, g1, b1, Cs);

    // fused QKV: 1536 blocks
    gemm_qkv<<<dim3(64, 24), blk, 0, stream>>>(Cs, WqT, bq, bk, bv, Qb, Kb, Vb, 1024);

    // per-head V transpose: V(S1) -> Vt(S2)
    transpose_bf16<<<dim3(1, 16, 128), blk, 0, stream>>>(Vb, Cs, 1024, 64, 65536, 65536);

    // flash attention: Q(d_out), K(S0), Vt(S2) -> Ob(S1)
    attn_kernel<<<dim3(8, 128), blk, 0, stream>>>(Qb, Kb, Cs, Ob);

    // W2 -> 4 chunked transposes (K-chunk layout) into dead K slot
    transpose_f32_bf16<<<dim3(16, 16, 4), blk, 0, stream>>>(
        W2, W2T, 1024, 1024, 1024*1024, 1024*1024);

    // proj + residual: Ob @ Wp + bp + x -> x2 (f32, d_out)
    gemm_bt<1><<<dim3(64, 8), blk, 0, stream>>>(Ob, WpT, bp, x, nullptr, x2, 1024, 1024);

    // LN2: x2 -> h2 (Cs)
    ln_kernel<<<8192, blk, 0, stream>>>(x2, g2, b2, h2);

    // MLP: N-chunked FC1 / K-chunked FC2 (all launches 512 blocks)
    for (int c = 0; c < 4; ++c) {
        gemm_bt<2><<<dim3(64, 8), blk, 0, stream>>>(
            h2, W1T + (size_t)c * 1024 * 1024, c1 + c * 1024, nullptr,
            hid, nullptr, 1024, 1024);
        if (c == 0)
            gemm_bt<1><<<dim3(64, 8), blk, 0, stream>>>(
                hid, W2T, c2, outf, nullptr, outf, 1024, 1024);
        else
            gemm_bt<5><<<dim3(64, 8), blk, 0, stream>>>(
                hid, W2T + (size_t)c * 1024 * 1024, c2, nullptr, nullptr,
                outf, 1024, 1024);
    }
}

// Round 6
// 616.577 us; speedup vs baseline: 1.4846x; 1.0808x over previous
//
#include <hip/hip_runtime.h>
#include <hip/hip_bf16.h>
#include <math.h>

typedef __bf16 bf16_t;
typedef __bf16 bf16x4 __attribute__((ext_vector_type(4)));
typedef __bf16 bf16x8 __attribute__((ext_vector_type(8)));
typedef float  f32x4  __attribute__((ext_vector_type(4)));

typedef __attribute__((address_space(1))) const void GVoid;
typedef __attribute__((address_space(3))) void LVoid;

__device__ __forceinline__ void gld16(const void* g, void* l) {
    __builtin_amdgcn_global_load_lds((GVoid*)g, (LVoid*)l, 16, 0, 0);
}

__device__ __forceinline__ float gelu_exact(float v) {
    return 0.5f * v * (1.0f + erff(v * 0.7071067811865475f));
}

// ---------------------------------------------------------------------------
// Tiled transpose + downcast (batched): f32 (R x C) -> bf16 (C x R) per batch.
// ---------------------------------------------------------------------------
__global__ __launch_bounds__(256) void transpose_f32_bf16(
    const float* __restrict__ in, bf16_t* __restrict__ out,
    int R, int C, size_t inBatch, size_t outBatch)
{
    __shared__ bf16_t tile[64][65];
    const float* src = in  + (size_t)blockIdx.z * inBatch;
    bf16_t*      dst = out + (size_t)blockIdx.z * outBatch;
    const int r0 = blockIdx.y * 64, c0 = blockIdx.x * 64;
    const int t = threadIdx.x, tc = t & 63, tr = t >> 6;
#pragma unroll
    for (int i = 0; i < 16; ++i) {
        int r = tr + i * 4;
        tile[r][tc] = (bf16_t)src[(size_t)(r0 + r) * C + c0 + tc];
    }
    __syncthreads();
#pragma unroll
    for (int i = 0; i < 16; ++i) {
        int r = tr + i * 4;
        dst[(size_t)(c0 + r) * R + r0 + tc] = tile[tc][r];
    }
}

// ---------------------------------------------------------------------------
// Tiled bf16 transpose (batched): per-head V (1024x64) -> (64x1024).
// ---------------------------------------------------------------------------
__global__ __launch_bounds__(256) void transpose_bf16(
    const bf16_t* __restrict__ in, bf16_t* __restrict__ out,
    int R, int C, size_t inBatch, size_t outBatch)
{
    __shared__ __align__(16) bf16_t tile[64][65];
    const bf16_t* src = in  + (size_t)blockIdx.z * inBatch;
    bf16_t*       dst = out + (size_t)blockIdx.z * outBatch;
    const int r0 = blockIdx.y * 64, c0 = blockIdx.x * 64;
    const int t = threadIdx.x, tc = t & 63, tr = t >> 6;
#pragma unroll
    for (int i = 0; i < 16; ++i) {
        int r = tr + i * 4;
        tile[r][tc] = src[(size_t)(r0 + r) * C + c0 + tc];
    }
    __syncthreads();
#pragma unroll
    for (int i = 0; i < 16; ++i) {
        int r = tr + i * 4;
        dst[(size_t)(c0 + r) * R + r0 + tc] = tile[tc][r];
    }
}

// ---------------------------------------------------------------------------
// LayerNorm rows of 1024: f32 in -> bf16 out. One 256-thread block / row.
// ---------------------------------------------------------------------------
__global__ __launch_bounds__(256) void ln_kernel(
    const float* __restrict__ x, const float* __restrict__ g,
    const float* __restrict__ b, bf16_t* __restrict__ out)
{
    const int row = blockIdx.x, t = threadIdx.x;
    const float* xr = x + (size_t)row * 1024;
    float v[4];
#pragma unroll
    for (int i = 0; i < 4; ++i) v[i] = xr[t * 4 + i];
    float s = v[0] + v[1] + v[2] + v[3];
    float s2 = v[0]*v[0] + v[1]*v[1] + v[2]*v[2] + v[3]*v[3];
#pragma unroll
    for (int o = 1; o < 64; o <<= 1) { s += __shfl_xor(s, o); s2 += __shfl_xor(s2, o); }
    __shared__ float red[8];
    if ((t & 63) == 0) { red[t >> 6] = s; red[4 + (t >> 6)] = s2; }
    __syncthreads();
    s  = red[0] + red[1] + red[2] + red[3];
    s2 = red[4] + red[5] + red[6] + red[7];
    const float mean = s * (1.f / 1024.f);
    const float var  = fmaxf(s2 * (1.f / 1024.f) - mean * mean, 0.f);
    const float rstd = rsqrtf(var + 1e-5f);
#pragma unroll
    for (int i = 0; i < 4; ++i) {
        int c = t * 4 + i;
        out[(size_t)row * 1024 + c] =
            (bf16_t)((v[i] - mean) * rstd * g[c] + b[c]);
    }
}

// ---------------------------------------------------------------------------
// GEMM: C(M,N) = A(M,K) @ B(K,N), B transposed: Bt(N,K) row-major bf16.
// 128x128 tile, BK=32, 4 waves (2x2), 16x16x32 bf16 MFMA.
// MODE 1: out_f  = acc + bias + resid_f   (resid may alias out)
// MODE 2: out_bf = gelu(acc + bias)
// MODE 5: out_f += acc                    (K-chunk accumulation)
// ---------------------------------------------------------------------------
template <int MODE>
__global__ __launch_bounds__(256) void gemm_bt(
    const bf16_t* __restrict__ A, const bf16_t* __restrict__ Bt,
    const float* __restrict__ bias, const float* resid_f,
    bf16_t* __restrict__ out_bf, float* out_f, int N, int K)
{
    __shared__ __align__(16) bf16_t As[128 * 32];
    __shared__ __align__(16) bf16_t Bs[128 * 32];
    const int t = threadIdx.x;
    const int wv = t >> 6, ln = t & 63;
    const int wx = wv & 1, wy = wv >> 1;
    const int l16 = ln & 15, quad = ln >> 4;
    const int m0 = blockIdx.x * 128, n0 = blockIdx.y * 128;

    f32x4 acc[4][4];
#pragma unroll
    for (int i = 0; i < 4; ++i)
#pragma unroll
        for (int j = 0; j < 4; ++j) acc[i][j] = f32x4{0.f, 0.f, 0.f, 0.f};

    const int arow = t >> 2;
    const int acol = (t & 3) << 3;
    const bf16_t* gA = A  + (size_t)(m0 + arow) * K + acol;
    const bf16_t* gB = Bt + (size_t)(n0 + arow) * K + acol;
    char* ldsA = (char*)As + wv * 1024;
    char* ldsB = (char*)Bs + wv * 1024;

    for (int kk = 0; kk < K; kk += 32) {
        __syncthreads();
        gld16(gA + kk,                 ldsA);
        gld16(gA + (size_t)64*K + kk,  ldsA + 4096);
        gld16(gB + kk,                 ldsB);
        gld16(gB + (size_t)64*K + kk,  ldsB + 4096);
        __syncthreads();

        bf16x8 af[4], bfr[4];
        const bf16_t* Ab = As + (wy * 64 + l16) * 32 + quad * 8;
        const bf16_t* Bb = Bs + (wx * 64 + l16) * 32 + quad * 8;
#pragma unroll
        for (int i = 0; i < 4; ++i) af[i]  = *(const bf16x8*)(Ab + i * 16 * 32);
#pragma unroll
        for (int j = 0; j < 4; ++j) bfr[j] = *(const bf16x8*)(Bb + j * 16 * 32);
#pragma unroll
        for (int i = 0; i < 4; ++i)
#pragma unroll
            for (int j = 0; j < 4; ++j)
                acc[i][j] = __builtin_amdgcn_mfma_f32_16x16x32_bf16(
                    af[i], bfr[j], acc[i][j], 0, 0, 0);
    }

#pragma unroll
    for (int i = 0; i < 4; ++i) {
        const int rowb = m0 + wy * 64 + i * 16 + quad * 4;
#pragma unroll
        for (int j = 0; j < 4; ++j) {
            const int col = n0 + wx * 64 + j * 16 + l16;
            const float bc = bias[col];
#pragma unroll
            for (int r = 0; r < 4; ++r) {
                const size_t idx = (size_t)(rowb + r) * N + col;
                float vv = acc[i][j][r] + bc;
                if (MODE == 1) out_f[idx] = vv + resid_f[idx];
                else if (MODE == 2) out_bf[idx] = (bf16_t)gelu_exact(vv);
                else out_f[idx] += acc[i][j][r];
            }
        }
    }
}

// ---------------------------------------------------------------------------
// Fused QKV GEMM: A(8192x1024) @ [Wq|Wk|Wv]^T (3072x1024 concat Bt).
// Per-block output segment is uniform (n0 multiple of 128, segs of 1024).
// ---------------------------------------------------------------------------
__global__ __launch_bounds__(256) void gemm_qkv(
    const bf16_t* __restrict__ A, const bf16_t* __restrict__ Bt,
    const float* __restrict__ bq, const float* __restrict__ bk,
    const float* __restrict__ bv,
    bf16_t* __restrict__ Qo, bf16_t* __restrict__ Ko, bf16_t* __restrict__ Vo,
    int K)
{
    __shared__ __align__(16) bf16_t As[128 * 32];
    __shared__ __align__(16) bf16_t Bs[128 * 32];
    const int t = threadIdx.x;
    const int wv = t >> 6, ln = t & 63;
    const int wx = wv & 1, wy = wv >> 1;
    const int l16 = ln & 15, quad = ln >> 4;
    const int m0 = blockIdx.x * 128, n0 = blockIdx.y * 128;

    f32x4 acc[4][4];
#pragma unroll
    for (int i = 0; i < 4; ++i)
#pragma unroll
        for (int j = 0; j < 4; ++j) acc[i][j] = f32x4{0.f, 0.f, 0.f, 0.f};

    const int arow = t >> 2;
    const int acol = (t & 3) << 3;
    const bf16_t* gA = A  + (size_t)(m0 + arow) * K + acol;
    const bf16_t* gB = Bt + (size_t)(n0 + arow) * K + acol;
    char* ldsA = (char*)As + wv * 1024;
    char* ldsB = (char*)Bs + wv * 1024;

    for (int kk = 0; kk < K; kk += 32) {
        __syncthreads();
        gld16(gA + kk,                 ldsA);
        gld16(gA + (size_t)64*K + kk,  ldsA + 4096);
        gld16(gB + kk,                 ldsB);
        gld16(gB + (size_t)64*K + kk,  ldsB + 4096);
        __syncthreads();

        bf16x8 af[4], bfr[4];
        const bf16_t* Ab = As + (wy * 64 + l16) * 32 + quad * 8;
        const bf16_t* Bb = Bs + (wx * 64 + l16) * 32 + quad * 8;
#pragma unroll
        for (int i = 0; i < 4; ++i) af[i]  = *(const bf16x8*)(Ab + i * 16 * 32);
#pragma unroll
        for (int j = 0; j < 4; ++j) bfr[j] = *(const bf16x8*)(Bb + j * 16 * 32);
#pragma unroll
        for (int i = 0; i < 4; ++i)
#pragma unroll
            for (int j = 0; j < 4; ++j)
                acc[i][j] = __builtin_amdgcn_mfma_f32_16x16x32_bf16(
                    af[i], bfr[j], acc[i][j], 0, 0, 0);
    }

    const int which = n0 >> 10;                         // block-uniform
    const float* bias = which == 0 ? bq : (which == 1 ? bk : bv);
    bf16_t* outp      = which == 0 ? Qo : (which == 1 ? Ko : Vo);
    const int nloc = n0 & 1023;
#pragma unroll
    for (int i = 0; i < 4; ++i) {
        const int rowb = m0 + wy * 64 + i * 16 + quad * 4;
#pragma unroll
        for (int j = 0; j < 4; ++j) {
            const int col = nloc + wx * 64 + j * 16 + l16;
            const float bc = bias[col];
#pragma unroll
            for (int r = 0; r < 4; ++r)
                outp[(size_t)(rowb + r) * 1024 + col] = (bf16_t)(acc[i][j][r] + bc);
        }
    }
}

// ---------------------------------------------------------------------------
// Flash attention, conflict-free LDS (K stride 72, V/P stride 136).
// Computes S^T = K.Q^T so P leaves MFMA with 4 consecutive k per lane.
// ---------------------------------------------------------------------------
__global__ __launch_bounds__(256, 2) void attn_kernel(
    const bf16_t* __restrict__ Q, const bf16_t* __restrict__ K,
    const bf16_t* __restrict__ Vt, bf16_t* __restrict__ O)
{
    __shared__ __align__(16) bf16_t smem[26112];
    bf16_t* Vs = smem;             // 64*136
    bf16_t* Ks = smem + 8704;      // 128*72
    bf16_t* Ps = smem + 8704;      // 128*136 (overlays Ks)

    const int t = threadIdx.x;
    const int wv = t >> 6, ln = t & 63;
    const int l16 = ln & 15, quad = ln >> 4;
    const int qt = blockIdx.x, bh = blockIdx.y;
    const size_t hb = (size_t)bh << 16;

    bf16x8 qf[2][2];
#pragma unroll
    for (int rt = 0; rt < 2; ++rt)
#pragma unroll
        for (int ks = 0; ks < 2; ++ks)
            qf[rt][ks] = *(const bf16x8*)(Q + hb +
                (size_t)(qt*128 + wv*32 + rt*16 + l16) * 64 + ks*32 + quad*8);

    float m_run[2] = {-INFINITY, -INFINITY};
    float l_run[2] = {0.f, 0.f};
    f32x4 acc_o[2][4];
#pragma unroll
    for (int rt = 0; rt < 2; ++rt)
#pragma unroll
        for (int dt = 0; dt < 4; ++dt) acc_o[rt][dt] = f32x4{0.f, 0.f, 0.f, 0.f};

    const int krow = t >> 3, kcol = (t & 7) << 3;
    const int vrow = t >> 4, vcol = (t & 15) << 3;
    const float sc = 0.125f;

    for (int j = 0; j < 8; ++j) {
        bf16x8 kg[4], vg[4];
#pragma unroll
        for (int i = 0; i < 4; ++i) {
            kg[i] = *(const bf16x8*)(K  + hb + (size_t)(j*128 + i*32 + krow)*64 + kcol);
            vg[i] = *(const bf16x8*)(Vt + hb + (size_t)(i*16 + vrow)*1024 + j*128 + vcol);
        }
        __syncthreads();
#pragma unroll
        for (int i = 0; i < 4; ++i) {
            *(bf16x8*)(Ks + (i*32 + krow)*72 + kcol)  = kg[i];
            *(bf16x8*)(Vs + (i*16 + vrow)*136 + vcol) = vg[i];
        }
        __syncthreads();

        f32x4 accs[8][2];
#pragma unroll
        for (int nt = 0; nt < 8; ++nt)
#pragma unroll
            for (int rt = 0; rt < 2; ++rt) accs[nt][rt] = f32x4{0.f, 0.f, 0.f, 0.f};
#pragma unroll
        for (int ks = 0; ks < 2; ++ks)
#pragma unroll
            for (int nt = 0; nt < 8; ++nt) {
                bf16x8 kf = *(const bf16x8*)(Ks + (nt*16 + l16)*72 + ks*32 + quad*8);
#pragma unroll
                for (int rt = 0; rt < 2; ++rt)
                    accs[nt][rt] = __builtin_amdgcn_mfma_f32_16x16x32_bf16(
                        kf, qf[rt][ks], accs[nt][rt], 0, 0, 0);
            }

#pragma unroll
        for (int rt = 0; rt < 2; ++rt) {
            float mx = -INFINITY;
#pragma unroll
            for (int nt = 0; nt < 8; ++nt)
#pragma unroll
                for (int r = 0; r < 4; ++r) mx = fmaxf(mx, accs[nt][rt][r]);
            mx *= sc;
            mx = fmaxf(mx, __shfl_xor(mx, 16));
            mx = fmaxf(mx, __shfl_xor(mx, 32));
            const float mnew  = fmaxf(m_run[rt], mx);
            const float alpha = __expf(m_run[rt] - mnew);
            m_run[rt] = mnew;
            float rs = 0.f;
#pragma unroll
            for (int nt = 0; nt < 8; ++nt)
#pragma unroll
                for (int r = 0; r < 4; ++r) {
                    float p = __expf(accs[nt][rt][r] * sc - mnew);
                    accs[nt][rt][r] = p;
                    rs += p;
                }
            rs += __shfl_xor(rs, 16);
            rs += __shfl_xor(rs, 32);
            l_run[rt] = l_run[rt] * alpha + rs;
#pragma unroll
            for (int r = 0; r < 4; ++r) {
                const float af = __shfl(alpha, quad*4 + r, 16);
#pragma unroll
                for (int dt = 0; dt < 4; ++dt) acc_o[rt][dt][r] *= af;
            }
        }

        __syncthreads();
#pragma unroll
        for (int rt = 0; rt < 2; ++rt) {
            const int mrow = wv*32 + rt*16 + l16;
#pragma unroll
            for (int nt = 0; nt < 8; ++nt) {
                bf16x4 pk;
#pragma unroll
                for (int r = 0; r < 4; ++r) pk[r] = (bf16_t)accs[nt][rt][r];
                *(bf16x4*)(Ps + mrow*136 + nt*16 + quad*4) = pk;
            }
        }
#pragma unroll
        for (int ks = 0; ks < 4; ++ks) {
            bf16x8 ap[2];
#pragma unroll
            for (int rt = 0; rt < 2; ++rt)
                ap[rt] = *(const bf16x8*)(Ps + (wv*32 + rt*16 + l16)*136 + ks*32 + quad*8);
#pragma unroll
            for (int dt = 0; dt < 4; ++dt) {
                bf16x8 bvv = *(const bf16x8*)(Vs + (dt*16 + l16)*136 + ks*32 + quad*8);
#pragma unroll
                for (int rt = 0; rt < 2; ++rt)
                    acc_o[rt][dt] = __builtin_amdgcn_mfma_f32_16x16x32_bf16(
                        ap[rt], bvv, acc_o[rt][dt], 0, 0, 0);
            }
        }
    }

    const int b = bh >> 4, h = bh & 15;
#pragma unroll
    for (int rt = 0; rt < 2; ++rt) {
#pragma unroll
        for (int r = 0; r < 4; ++r) {
            const float inv = 1.f / __shfl(l_run[rt], quad*4 + r, 16);
            const int m = qt*128 + wv*32 + rt*16 + quad*4 + r;
#pragma unroll
            for (int dt = 0; dt < 4; ++dt) {
                const int d = dt*16 + l16;
                O[((size_t)b*1024 + m)*1024 + h*64 + d] =
                    (bf16_t)(acc_o[rt][dt][r] * inv);
            }
        }
    }
}

// ---------------------------------------------------------------------------
extern "C" void kernel_launch(void* const* d_in, const int* in_sizes, int n_in,
                              void* d_out, int out_size, void* d_ws, size_t ws_size,
                              hipStream_t stream)
{
    (void)in_sizes; (void)n_in;
    const size_t MB = 1ull << 20;
    if (ws_size < 64 * MB) {
        hipMemsetAsync(d_out, 0, (size_t)out_size * sizeof(float), stream);
        return;
    }

    const float* x  = (const float*)d_in[0];
    const float* g1 = (const float*)d_in[1];
    const float* b1 = (const float*)d_in[2];
    const float* Wq = (const float*)d_in[3];
    const float* bq = (const float*)d_in[4];
    const float* Wk = (const float*)d_in[5];
    const float* bk = (const float*)d_in[6];
    const float* Wv = (const float*)d_in[7];
    const float* bv = (const float*)d_in[8];
    const float* Wp = (const float*)d_in[9];
    const float* bp = (const float*)d_in[10];
    const float* g2 = (const float*)d_in[11];
    const float* b2 = (const float*)d_in[12];
    const float* W1 = (const float*)d_in[13];
    const float* c1 = (const float*)d_in[14];
    const float* W2 = (const float*)d_in[15];
    const float* c2 = (const float*)d_in[16];

    // Workspace (64 MB):
    //   0-16  (S0): Kb            -> hid[0:16MB]
    //   16-32 (S1): Vb -> Ob      -> hid[16:32MB]   (hid = 8192x2048 bf16)
    //   32-48 (S2): h1 -> Vt -> h2
    //   48-54     : WqT|WkT|WvT (QKV fused Bt)  -> W2T (8 MB @48-56, after proj)
    //   54-56     : WpT
    //   56-64     : W1T (4096x1024)
    //   d_out (32 MB f32): Qb bf16 -> x2 f32 -> final out (FC2 RMW in place)
    char* ws = (char*)d_ws;
    bf16_t* Kb  = (bf16_t*)(ws);
    bf16_t* Vb  = (bf16_t*)(ws + 16 * MB);
    bf16_t* Cs  = (bf16_t*)(ws + 32 * MB);
    bf16_t* WqT = (bf16_t*)(ws + 48 * MB);
    bf16_t* WpT = (bf16_t*)(ws + 54 * MB);
    bf16_t* W1T = (bf16_t*)(ws + 56 * MB);
    bf16_t* W2T = (bf16_t*)(ws + 48 * MB);   // after WqkvT/WpT dead
    bf16_t* Qb  = (bf16_t*)d_out;
    bf16_t* Ob  = Vb;
    bf16_t* hid = Kb;                        // 32 MB spanning S0+S1
    bf16_t* h2  = Cs;
    float*  x2  = (float*)d_out;
    float*  outf = (float*)d_out;

    const dim3 blk(256);

    // weight transposes (f32 -> bf16, (N,K)); Wq/Wk/Wv land contiguous
    transpose_f32_bf16<<<dim3(16, 16, 1), blk, 0, stream>>>(Wq, WqT,              1024, 1024, 0, 0);
    transpose_f32_bf16<<<dim3(16, 16, 1), blk, 0, stream>>>(Wk, WqT + 1024*1024,  1024, 1024, 0, 0);
    transpose_f32_bf16<<<dim3(16, 16, 1), blk, 0, stream>>>(Wv, WqT + 2*1024*1024, 1024, 1024, 0, 0);
    transpose_f32_bf16<<<dim3(16, 16, 1), blk, 0, stream>>>(Wp, WpT,              1024, 1024, 0, 0);
    transpose_f32_bf16<<<dim3(64, 16, 1), blk, 0, stream>>>(W1, W1T,              1024, 4096, 0, 0);

    // LN1: x -> h1 (Cs)
    ln_kernel<<<8192, blk, 0, stream>>>(x, g1, b1, Cs);

    // fused QKV: 1536 blocks
    gemm_qkv<<<dim3(64, 24), blk, 0, stream>>>(Cs, WqT, bq, bk, bv, Qb, Kb, Vb, 1024);

    // per-head V transpose: V(S1) -> Vt(S2)
    transpose_bf16<<<dim3(1, 16, 128), blk, 0, stream>>>(Vb, Cs, 1024, 64, 65536, 65536);

    // flash attention: Q(d_out), K(S0), Vt(S2) -> Ob(S1)
    attn_kernel<<<dim3(8, 128), blk, 0, stream>>>(Qb, Kb, Cs, Ob);

    // proj + residual: Ob @ Wp + bp + x -> x2 (f32, d_out)
    gemm_bt<1><<<dim3(64, 8), blk, 0, stream>>>(Ob, WpT, bp, x, nullptr, x2, 1024, 1024);

    // W2 -> 2 K-chunks (1024 x 2048 each), into dead weights arena @48-56
    transpose_f32_bf16<<<dim3(16, 32, 2), blk, 0, stream>>>(
        W2, W2T, 2048, 1024, 2048*1024, 2048*1024);

    // LN2: x2 -> h2 (Cs)
    ln_kernel<<<8192, blk, 0, stream>>>(x2, g2, b2, h2);

    // MLP: 2 K-chunks of 2048; hid = 8192x2048 bf16 (32 MB @ S0+S1)
    for (int c = 0; c < 2; ++c) {
        gemm_bt<2><<<dim3(64, 16), blk, 0, stream>>>(
            h2, W1T + (size_t)c * 2048 * 1024, c1 + c * 2048, nullptr,
            hid, nullptr, 2048, 1024);
        if (c == 0)
            gemm_bt<1><<<dim3(64, 8), blk, 0, stream>>>(
                hid, W2T, c2, outf, nullptr, outf, 1024, 2048);
        else
            gemm_bt<5><<<dim3(64, 8), blk, 0, stream>>>(
                hid, W2T + (size_t)2048 * 1024, c2, nullptr, nullptr,
                outf, 1024, 2048);
    }
}